// Round 10
// baseline (541.272 us; speedup 1.0000x reference)
//
#include <hip/hip_runtime.h>
#include <hip/hip_bf16.h>
#include <stdint.h>

#define N_NODES 50000
#define E_EDGES 800000

typedef short s16x8 __attribute__((ext_vector_type(8)));
typedef float f32x4 __attribute__((ext_vector_type(4)));

__device__ __forceinline__ float bf2f(unsigned int u) {
    return __uint_as_float(u << 16);
}
__device__ __forceinline__ unsigned short f2bf(float f) {
    unsigned int u = __float_as_uint(f);
    unsigned int r = (u + 0x7FFFu + ((u >> 16) & 1u)) >> 16;
    return (unsigned short)r;
}

// Hardware XCD id (0..7) — verified readable on MI355X [learn_hip m09].
__device__ __forceinline__ int xcc_id() {
    unsigned v;
    asm volatile("s_getreg_b32 %0, hwreg(HW_REG_XCC_ID)" : "=s"(v));
    return (int)(v & 7);
}

// ---------------- CSR construction ----------------

__global__ void hist_deg(const int* __restrict__ dst, int* __restrict__ deg) {
    int e = blockIdx.x * blockDim.x + threadIdx.x;
    if (e >= E_EDGES) return;
    atomicAdd(&deg[dst[e]], 1);
}

__global__ __launch_bounds__(1024) void scan1(const int* __restrict__ deg,
                                              int* __restrict__ lexcl,
                                              int* __restrict__ btot) {
    __shared__ int wsum[16];
    int gid = blockIdx.x * 1024 + threadIdx.x;
    int lane = threadIdx.x & 63, wid = threadIdx.x >> 6;
    int v = (gid < N_NODES) ? deg[gid] : 0;
    int x = v;
#pragma unroll
    for (int off = 1; off < 64; off <<= 1) {
        int t = __shfl_up(x, off);
        if (lane >= off) x += t;
    }
    if (lane == 63) wsum[wid] = x;
    __syncthreads();
    if (wid == 0 && lane < 16) {
        int w = wsum[lane];
#pragma unroll
        for (int off = 1; off < 16; off <<= 1) {
            int t = __shfl_up(w, off);
            if (lane >= off) w += t;
        }
        wsum[lane] = w;
    }
    __syncthreads();
    int excl = x - v + (wid ? wsum[wid - 1] : 0);
    if (gid < N_NODES) lexcl[gid] = excl;
    if (threadIdx.x == 0) btot[blockIdx.x] = wsum[15];
}

__global__ void scan2(const int* __restrict__ btot, int* __restrict__ bbase,
                      int nb) {
    int lane = threadIdx.x;
    int v = (lane < nb) ? btot[lane] : 0;
    int x = v;
#pragma unroll
    for (int off = 1; off < 64; off <<= 1) {
        int t = __shfl_up(x, off);
        if (lane >= off) x += t;
    }
    if (lane < nb) bbase[lane] = x - v;
}

__global__ void scan3(const int* __restrict__ lexcl, const int* __restrict__ bbase,
                      int* __restrict__ rowptr, int* __restrict__ cursor) {
    int gid = blockIdx.x * blockDim.x + threadIdx.x;
    if (gid < N_NODES) {
        int r = lexcl[gid] + bbase[gid >> 10];
        rowptr[gid] = r;
        cursor[gid] = r;
    }
    if (gid == 0) rowptr[N_NODES] = E_EDGES;
}

__global__ void fill_csr(const int* __restrict__ src, const int* __restrict__ dst,
                         int* __restrict__ cursor, unsigned short* __restrict__ perm) {
    int e = blockIdx.x * blockDim.x + threadIdx.x;
    if (e >= E_EDGES) return;
    int d = dst[e];
    int pos = atomicAdd(&cursor[d], 1);
    perm[pos] = (unsigned short)src[e];
}

// ---- Slice x row-major [N,128] -> fs[8][N][16] (contiguous 3.2 MB per slice)
__global__ void slice_x(const float* __restrict__ x, float* __restrict__ fs) {
    int tid = blockIdx.x * 256 + threadIdx.x;
    if (tid >= N_NODES * 32) return;
    int k4 = tid & 3;
    int node = (tid >> 2) % N_NODES;
    int g = (tid >> 2) / N_NODES;
    *(float4*)(fs + ((size_t)g * N_NODES + node) * 16 + k4 * 4) =
        *(const float4*)(x + (size_t)node * 128 + g * 16 + k4 * 4);
}

// ---------------- XCC-confined, one-node-per-wave aggregation ----------------
// Wave layout: lane = edge_slot(0..15)*4 + chan_lane(0..3).
// One load instruction gathers 16 edges x 64 B; deg<=16 -> single iteration,
// ZERO cross-node degree divergence. shfl_xor reduce over edge slots.
// Waves claim 32-node chunks from a line-padded per-slice counter.
__global__ __launch_bounds__(256) void gather_node(
    const float* __restrict__ fs,        // [8][N][16] slice-major
    const int* __restrict__ rowptr,
    const unsigned short* __restrict__ perm,
    int* __restrict__ ctr,               // padded: counter g at ctr[g*16]
    float* __restrict__ out) {           // [N,128] row-major
    int g = xcc_id();
    int lane = threadIdx.x & 63;
    int es = lane >> 2;                  // edge slot 0..15
    int k4 = (lane & 3) * 4;             // channel offset within slice
    const float* fp = fs + (size_t)g * N_NODES * 16 + k4;
    int* myctr = ctr + g * 16;
    for (;;) {
        int chunk;
        if (lane == 0) chunk = atomicAdd(myctr, 1);
        chunk = __shfl(chunk, 0);
        int n0 = chunk * 32;
        if (n0 >= N_NODES) return;
        int n1 = n0 + 32; if (n1 > N_NODES) n1 = N_NODES;
        for (int node = n0; node < n1; node++) {
            int beg = rowptr[node], end = rowptr[node + 1];
            f32x4 acc = {0.f, 0.f, 0.f, 0.f};
            if (es == 0) acc = *(const f32x4*)(fp + (size_t)node * 16);
            for (int j = beg + es; j < end; j += 16) {
                int s = perm[j];
                f32x4 v = *(const f32x4*)(fp + (size_t)s * 16);
                acc += v;
            }
#pragma unroll
            for (int m = 4; m <= 32; m <<= 1) {
                acc[0] += __shfl_xor(acc[0], m);
                acc[1] += __shfl_xor(acc[1], m);
                acc[2] += __shfl_xor(acc[2], m);
                acc[3] += __shfl_xor(acc[3], m);
            }
            if (es == 0) {
                f32x4* dst4 = (f32x4*)(out + (size_t)node * 128 + g * 16 + k4);
                __builtin_nontemporal_store(acc, dst4);
            }
        }
    }
}

// ---- Weight pre-split (fused) ----
__device__ __forceinline__ void prep_one(const float* __restrict__ W,
                                         unsigned short* __restrict__ Whi,
                                         unsigned short* __restrict__ Wlo,
                                         int K, int F, int Fpad, int i) {
    int S = K / 32, T = Fpad / 16;
    int total = T * S * 64;
    if (i >= total) return;
    int lane = i & 63;
    int s = (i >> 6) % S;
    int t = (i >> 6) / S;
    int col = t * 16 + (lane & 15);
    int k0 = s * 32 + (lane >> 4) * 8;
    s16x8 vh, vl;
#pragma unroll
    for (int j = 0; j < 8; j++) {
        float w = (col < F) ? W[(size_t)(k0 + j) * F + col] : 0.f;
        unsigned short h = f2bf(w);
        float r = w - bf2f(h);
        vh[j] = (short)h;
        vl[j] = (short)f2bf(r);
    }
    *(s16x8*)(Whi + (size_t)i * 8) = vh;
    *(s16x8*)(Wlo + (size_t)i * 8) = vl;
}

__global__ void prep_all(const float* W1, const float* W2, const float* W3,
                         const float* W4, const float* Wl,
                         unsigned short* W1h, unsigned short* W1l,
                         unsigned short* W2h, unsigned short* W2l,
                         unsigned short* W3h, unsigned short* W3l,
                         unsigned short* W4h, unsigned short* W4l,
                         unsigned short* Wlh, unsigned short* Wll) {
    int b = blockIdx.x, t = threadIdx.x;
    if (b < 8)       prep_one(W1, W1h, W1l, 128, 128, 128, b * 256 + t);
    else if (b < 16) prep_one(W2, W2h, W2l, 128, 128, 128, (b - 8) * 256 + t);
    else if (b < 32) prep_one(W3, W3h, W3l, 128, 256, 256, (b - 16) * 256 + t);
    else if (b < 64) prep_one(W4, W4h, W4l, 256, 256, 256, (b - 32) * 256 + t);
    else             prep_one(Wl, Wlh, Wll, 256, 40, 48, (b - 64) * 256 + t);
}

// ---- GEMM, split-precision bf16 MFMA; 16 rows/wave; CSPLIT column chunks.
template <int K, int F, int FOUT, bool RELU, int CSPLIT, bool SLICED_OUT>
__global__ __launch_bounds__(256) void gemm_split(
    const float* __restrict__ A,
    const unsigned short* __restrict__ Whi,
    const unsigned short* __restrict__ Wlo,
    const float* __restrict__ bias,
    float* __restrict__ out) {
    constexpr int S = K / 32;
    constexpr int T = F / 16;
    constexpr int TL = T / CSPLIT;
    int half = blockIdx.x % CSPLIT;
    int rc   = blockIdx.x / CSPLIT;
    int wave = threadIdx.x >> 6;
    int lane = threadIdx.x & 63;
    int row0 = rc * 64 + wave * 16;
    if (row0 >= N_NODES) return;
    int lm = lane & 15;
    int quad = lane >> 4;

    f32x4 acc[TL];
#pragma unroll
    for (int t = 0; t < TL; t++) {
        f32x4 z = {0.f, 0.f, 0.f, 0.f};
        acc[t] = z;
    }

#pragma unroll
    for (int s = 0; s < S; s++) {
        const float* ap = A + (size_t)(row0 + lm) * K + s * 32 + quad * 8;
        float4 x0 = *(const float4*)ap;
        float4 x1 = *(const float4*)(ap + 4);
        float v[8] = {x0.x, x0.y, x0.z, x0.w, x1.x, x1.y, x1.z, x1.w};
        s16x8 ah, al;
#pragma unroll
        for (int j = 0; j < 8; j++) {
            unsigned short h = f2bf(v[j]);
            float r = v[j] - bf2f(h);
            ah[j] = (short)h;
            al[j] = (short)f2bf(r);
        }
#pragma unroll
        for (int t = 0; t < TL; t++) {
            int tg = half * TL + t;
            const size_t fi = (size_t)((tg * S + s) * 64 + lane) * 8;
            const s16x8 bh = *(const s16x8*)(Whi + fi);
            const s16x8 bl = *(const s16x8*)(Wlo + fi);
            acc[t] = __builtin_amdgcn_mfma_f32_16x16x32_bf16(ah, bh, acc[t], 0, 0, 0);
            acc[t] = __builtin_amdgcn_mfma_f32_16x16x32_bf16(al, bh, acc[t], 0, 0, 0);
            acc[t] = __builtin_amdgcn_mfma_f32_16x16x32_bf16(ah, bl, acc[t], 0, 0, 0);
        }
    }

    int orow = row0 + quad * 4;
#pragma unroll
    for (int t = 0; t < TL; t++) {
        int tg = half * TL + t;
        int col = tg * 16 + lm;
        if (FOUT < F && col >= FOUT) continue;
        float bv = bias[col];
#pragma unroll
        for (int q = 0; q < 4; q++) {
            float vv = acc[t][q] + bv;
            if (RELU) vv = fmaxf(vv, 0.f);
            if (SLICED_OUT)
                out[((size_t)tg * N_NODES + orow + q) * 16 + lm] = vv;
            else
                out[(size_t)(orow + q) * FOUT + col] = vv;
        }
    }
}

extern "C" void kernel_launch(void* const* d_in, const int* in_sizes, int n_in,
                              void* d_out, int out_size, void* d_ws, size_t ws_size,
                              hipStream_t stream) {
    const float* x  = (const float*)d_in[0];
    const int* ei   = (const int*)d_in[1];
    const float* W1 = (const float*)d_in[2];
    const float* b1 = (const float*)d_in[3];
    const float* W2 = (const float*)d_in[4];
    const float* b2 = (const float*)d_in[5];
    const float* W3 = (const float*)d_in[6];
    const float* b3 = (const float*)d_in[7];
    const float* W4 = (const float*)d_in[8];
    const float* b4 = (const float*)d_in[9];
    const float* Wl = (const float*)d_in[10];
    const float* bl = (const float*)d_in[11];
    float* out = (float*)d_out;

    const int* src = ei;
    const int* dst = ei + E_EDGES;

    char* ws = (char*)d_ws;
    const size_t R = (size_t)N_NODES * 256 * 4;        // 51.2e6 B
    const size_t HALF = (size_t)N_NODES * 128;
    float* R1 = (float*)ws;
    float* R2 = (float*)(ws + R);
    float* hF   = R1;               // [N,128] agg out (layer 1 & 2)
    float* xs   = R1 + HALF;        // x sliced [8][N][16]
    float* hF2  = R1;
    float* h2b  = R1;               // [N,256]
    float* h1   = R2;               // [N,128]
    float* h1bs = R2 + HALF;        // h1b sliced [8][N][16]
    float* h2   = R2;               // [N,256]
    size_t off = 2 * R;
    unsigned short* W1h = (unsigned short*)(ws + off); off += 16384 * 2;
    unsigned short* W1l = (unsigned short*)(ws + off); off += 16384 * 2;
    unsigned short* W2h = (unsigned short*)(ws + off); off += 16384 * 2;
    unsigned short* W2l = (unsigned short*)(ws + off); off += 16384 * 2;
    unsigned short* W3h = (unsigned short*)(ws + off); off += 32768 * 2;
    unsigned short* W3l = (unsigned short*)(ws + off); off += 32768 * 2;
    unsigned short* W4h = (unsigned short*)(ws + off); off += 65536 * 2;
    unsigned short* W4l = (unsigned short*)(ws + off); off += 65536 * 2;
    unsigned short* Wlh = (unsigned short*)(ws + off); off += 12288 * 2;
    unsigned short* Wll = (unsigned short*)(ws + off); off += 12288 * 2;
    off = (off + 255) & ~(size_t)255;
    int* deg    = (int*)(ws + off); off += (size_t)(N_NODES + 1) * 4;
    int* cursor = (int*)(ws + off); off += (size_t)(N_NODES + 1) * 4;
    int* rowptr = (int*)(ws + off); off += (size_t)(N_NODES + 1) * 4;
    unsigned short* perm = (unsigned short*)(ws + off); off += (size_t)E_EDGES * 2;
    off = (off + 255) & ~(size_t)255;
    int* lexcl  = (int*)(ws + off); off += (size_t)N_NODES * 4;
    int* btot   = (int*)(ws + off); off += 64 * 4;
    int* bbase  = (int*)(ws + off); off += 64 * 4;
    int* ctr    = (int*)(ws + off); off += 256 * 4;   // 2 passes x 8 counters, 64B-padded
    (void)ws_size; (void)in_sizes; (void)n_in; (void)out_size;

    const int NB = (N_NODES + 1023) / 1024;

    // ---- CSR build + counters ----
    (void)hipMemsetAsync(deg, 0, (size_t)(N_NODES + 1) * 4, stream);
    (void)hipMemsetAsync(ctr, 0, 256 * 4, stream);
    hist_deg<<<(E_EDGES + 255) / 256, 256, 0, stream>>>(dst, deg);
    scan1<<<NB, 1024, 0, stream>>>(deg, lexcl, btot);
    scan2<<<1, 64, 0, stream>>>(btot, bbase, NB);
    scan3<<<(N_NODES + 255) / 256, 256, 0, stream>>>(lexcl, bbase, rowptr, cursor);
    fill_csr<<<(E_EDGES + 255) / 256, 256, 0, stream>>>(src, dst, cursor, perm);

    // ---- Weight pre-split + x slicing ----
    prep_all<<<70, 256, 0, stream>>>(W1, W2, W3, W4, Wl,
                                     W1h, W1l, W2h, W2l, W3h, W3l,
                                     W4h, W4l, Wlh, Wll);
    slice_x<<<(N_NODES * 32 + 255) / 256, 256, 0, stream>>>(x, xs);

    const int rowChunks = (N_NODES + 63) / 64;          // 782
    const int gatherBlocks = 2048;

    // ---- Layer 1 ----
    gather_node<<<gatherBlocks, 256, 0, stream>>>(xs, rowptr, perm, ctr, hF);
    gemm_split<128, 128, 128, true, 2, false><<<rowChunks * 2, 256, 0, stream>>>(hF, W1h, W1l, b1, h1);
    gemm_split<128, 128, 128, true, 2, true><<<rowChunks * 2, 256, 0, stream>>>(h1, W2h, W2l, b2, h1bs);

    // ---- Layer 2 ----
    gather_node<<<gatherBlocks, 256, 0, stream>>>(h1bs, rowptr, perm, ctr + 128, hF2);
    gemm_split<128, 256, 256, true, 2, false><<<rowChunks * 2, 256, 0, stream>>>(hF2, W3h, W3l, b3, h2);
    gemm_split<256, 256, 256, true, 2, false><<<rowChunks * 2, 256, 0, stream>>>(h2, W4h, W4l, b4, h2b);

    // ---- Final linear ----
    gemm_split<256, 48, 40, false, 1, false><<<rowChunks, 256, 0, stream>>>(h2b, Wlh, Wll, bl, out);
}

// Round 11
// 433.899 us; speedup vs baseline: 1.2475x; 1.2475x over previous
//
#include <hip/hip_runtime.h>
#include <hip/hip_bf16.h>
#include <stdint.h>

#define N_NODES 50000
#define E_EDGES 800000

typedef short s16x8 __attribute__((ext_vector_type(8)));
typedef float f32x4 __attribute__((ext_vector_type(4)));

__device__ __forceinline__ float bf2f(unsigned int u) {
    return __uint_as_float(u << 16);
}
__device__ __forceinline__ unsigned short f2bf(float f) {
    unsigned int u = __float_as_uint(f);
    unsigned int r = (u + 0x7FFFu + ((u >> 16) & 1u)) >> 16;
    return (unsigned short)r;
}

// ---------------- CSR construction ----------------

__global__ void hist_deg(const int* __restrict__ dst, int* __restrict__ deg) {
    int e = blockIdx.x * blockDim.x + threadIdx.x;
    if (e >= E_EDGES) return;
    atomicAdd(&deg[dst[e]], 1);
}

__global__ __launch_bounds__(1024) void scan1(const int* __restrict__ deg,
                                              int* __restrict__ lexcl,
                                              int* __restrict__ btot) {
    __shared__ int wsum[16];
    int gid = blockIdx.x * 1024 + threadIdx.x;
    int lane = threadIdx.x & 63, wid = threadIdx.x >> 6;
    int v = (gid < N_NODES) ? deg[gid] : 0;
    int x = v;
#pragma unroll
    for (int off = 1; off < 64; off <<= 1) {
        int t = __shfl_up(x, off);
        if (lane >= off) x += t;
    }
    if (lane == 63) wsum[wid] = x;
    __syncthreads();
    if (wid == 0 && lane < 16) {
        int w = wsum[lane];
#pragma unroll
        for (int off = 1; off < 16; off <<= 1) {
            int t = __shfl_up(w, off);
            if (lane >= off) w += t;
        }
        wsum[lane] = w;
    }
    __syncthreads();
    int excl = x - v + (wid ? wsum[wid - 1] : 0);
    if (gid < N_NODES) lexcl[gid] = excl;
    if (threadIdx.x == 0) btot[blockIdx.x] = wsum[15];
}

__global__ void scan2(const int* __restrict__ btot, int* __restrict__ bbase,
                      int nb) {
    int lane = threadIdx.x;
    int v = (lane < nb) ? btot[lane] : 0;
    int x = v;
#pragma unroll
    for (int off = 1; off < 64; off <<= 1) {
        int t = __shfl_up(x, off);
        if (lane >= off) x += t;
    }
    if (lane < nb) bbase[lane] = x - v;
}

__global__ void scan3(const int* __restrict__ lexcl, const int* __restrict__ bbase,
                      int* __restrict__ rowptr, int* __restrict__ cursor) {
    int gid = blockIdx.x * blockDim.x + threadIdx.x;
    if (gid < N_NODES) {
        int r = lexcl[gid] + bbase[gid >> 10];
        rowptr[gid] = r;
        cursor[gid] = r;
    }
    if (gid == 0) rowptr[N_NODES] = E_EDGES;
}

__global__ void fill_csr(const int* __restrict__ src, const int* __restrict__ dst,
                         int* __restrict__ cursor, unsigned short* __restrict__ perm) {
    int e = blockIdx.x * blockDim.x + threadIdx.x;
    if (e >= E_EDGES) return;
    int d = dst[e];
    int pos = atomicAdd(&cursor[d], 1);
    perm[pos] = (unsigned short)src[e];
}

// ---------------- Aggregation (R5 shape — best measured: 59 us) ----------------
// One wave per node, 2 fp32 channels per lane, 2 gather loads in flight.
__global__ __launch_bounds__(256) void gather_agg(
    const float* __restrict__ feat,
    const int* __restrict__ rowptr,
    const unsigned short* __restrict__ perm,
    float* __restrict__ out) {
    int node = (blockIdx.x * 256 + threadIdx.x) >> 6;
    if (node >= N_NODES) return;
    int lane = threadIdx.x & 63;
    const float2* fv = (const float2*)feat;
    float2 acc = fv[(size_t)node * 64 + lane];
    int beg = rowptr[node], end = rowptr[node + 1];
    for (int base = beg; base < end; base += 64) {
        int cnt = end - base; if (cnt > 64) cnt = 64;
        int pv = (base + lane < end) ? (int)perm[base + lane] : 0;
        int j = 0;
        for (; j + 1 < cnt; j += 2) {
            int s0 = __shfl(pv, j);
            int s1 = __shfl(pv, j + 1);
            float2 v0 = fv[(size_t)s0 * 64 + lane];
            float2 v1 = fv[(size_t)s1 * 64 + lane];
            acc.x += v0.x + v1.x;
            acc.y += v0.y + v1.y;
        }
        if (j < cnt) {
            int s = __shfl(pv, j);
            float2 v = fv[(size_t)s * 64 + lane];
            acc.x += v.x;
            acc.y += v.y;
        }
    }
    ((float2*)out)[(size_t)node * 64 + lane] = acc;
}

// ---- Weight pre-split (fused) ----
__device__ __forceinline__ void prep_one(const float* __restrict__ W,
                                         unsigned short* __restrict__ Whi,
                                         unsigned short* __restrict__ Wlo,
                                         int K, int F, int Fpad, int i) {
    int S = K / 32, T = Fpad / 16;
    int total = T * S * 64;
    if (i >= total) return;
    int lane = i & 63;
    int s = (i >> 6) % S;
    int t = (i >> 6) / S;
    int col = t * 16 + (lane & 15);
    int k0 = s * 32 + (lane >> 4) * 8;
    s16x8 vh, vl;
#pragma unroll
    for (int j = 0; j < 8; j++) {
        float w = (col < F) ? W[(size_t)(k0 + j) * F + col] : 0.f;
        unsigned short h = f2bf(w);
        float r = w - bf2f(h);
        vh[j] = (short)h;
        vl[j] = (short)f2bf(r);
    }
    *(s16x8*)(Whi + (size_t)i * 8) = vh;
    *(s16x8*)(Wlo + (size_t)i * 8) = vl;
}

__global__ void prep_all(const float* W1, const float* W2, const float* W3,
                         const float* W4, const float* Wl,
                         unsigned short* W1h, unsigned short* W1l,
                         unsigned short* W2h, unsigned short* W2l,
                         unsigned short* W3h, unsigned short* W3l,
                         unsigned short* W4h, unsigned short* W4l,
                         unsigned short* Wlh, unsigned short* Wll) {
    int b = blockIdx.x, t = threadIdx.x;
    if (b < 8)       prep_one(W1, W1h, W1l, 128, 128, 128, b * 256 + t);
    else if (b < 16) prep_one(W2, W2h, W2l, 128, 128, 128, (b - 8) * 256 + t);
    else if (b < 32) prep_one(W3, W3h, W3l, 128, 256, 256, (b - 16) * 256 + t);
    else if (b < 64) prep_one(W4, W4h, W4l, 256, 256, 256, (b - 32) * 256 + t);
    else             prep_one(Wl, Wlh, Wll, 256, 40, 48, (b - 64) * 256 + t);
}

// ---- GEMM, split-precision bf16 MFMA.
// RPW row-tiles (16 rows each) per wave, CSPLIT column chunks per grid.
// B-fragment L2 traffic = (M / (16*RPW)) * K*F*4B  -> RPW=2 halves it.
// acc VGPRs = TL*RPW*4 kept <= 64 to preserve occupancy (R6 lesson).
template <int K, int F, int FOUT, bool RELU, int CSPLIT, int RPW>
__global__ __launch_bounds__(256) void gemm_split(
    const float* __restrict__ A,
    const unsigned short* __restrict__ Whi,
    const unsigned short* __restrict__ Wlo,
    const float* __restrict__ bias,
    float* __restrict__ out) {
    constexpr int S = K / 32;
    constexpr int T = F / 16;
    constexpr int TL = T / CSPLIT;
    int half = blockIdx.x % CSPLIT;
    int rc   = blockIdx.x / CSPLIT;
    int wave = threadIdx.x >> 6;
    int lane = threadIdx.x & 63;
    int row0 = rc * (64 * RPW) + wave * (16 * RPW);
    if (row0 >= N_NODES) return;
    int lm = lane & 15;
    int quad = lane >> 4;
    bool rv[RPW];
#pragma unroll
    for (int r = 0; r < RPW; r++) rv[r] = (row0 + r * 16) < N_NODES;

    f32x4 acc[TL][RPW];
#pragma unroll
    for (int t = 0; t < TL; t++)
#pragma unroll
        for (int r = 0; r < RPW; r++) {
            f32x4 z = {0.f, 0.f, 0.f, 0.f};
            acc[t][r] = z;
        }

#pragma unroll
    for (int s = 0; s < S; s++) {
        s16x8 ah[RPW], al[RPW];
#pragma unroll
        for (int r = 0; r < RPW; r++) {
            int rr = rv[r] ? row0 + r * 16 : row0;
            const float* ap = A + (size_t)(rr + lm) * K + s * 32 + quad * 8;
            float4 x0 = *(const float4*)ap;
            float4 x1 = *(const float4*)(ap + 4);
            float v[8] = {x0.x, x0.y, x0.z, x0.w, x1.x, x1.y, x1.z, x1.w};
#pragma unroll
            for (int j = 0; j < 8; j++) {
                unsigned short h = f2bf(v[j]);
                float res = v[j] - bf2f(h);
                ah[r][j] = (short)h;
                al[r][j] = (short)f2bf(res);
            }
        }
#pragma unroll
        for (int t = 0; t < TL; t++) {
            int tg = half * TL + t;
            const size_t fi = (size_t)((tg * S + s) * 64 + lane) * 8;
            const s16x8 bh = *(const s16x8*)(Whi + fi);
            const s16x8 bl = *(const s16x8*)(Wlo + fi);
#pragma unroll
            for (int r = 0; r < RPW; r++) {
                acc[t][r] = __builtin_amdgcn_mfma_f32_16x16x32_bf16(ah[r], bh, acc[t][r], 0, 0, 0);
                acc[t][r] = __builtin_amdgcn_mfma_f32_16x16x32_bf16(al[r], bh, acc[t][r], 0, 0, 0);
                acc[t][r] = __builtin_amdgcn_mfma_f32_16x16x32_bf16(ah[r], bl, acc[t][r], 0, 0, 0);
            }
        }
    }

#pragma unroll
    for (int r = 0; r < RPW; r++) {
        if (!rv[r]) break;
        int orow = row0 + r * 16 + quad * 4;
#pragma unroll
        for (int t = 0; t < TL; t++) {
            int col = (half * TL + t) * 16 + lm;
            if (FOUT < F && col >= FOUT) continue;
            float bv = bias[col];
#pragma unroll
            for (int q = 0; q < 4; q++) {
                float vv = acc[t][r][q] + bv;
                if (RELU) vv = fmaxf(vv, 0.f);
                out[(size_t)(orow + q) * FOUT + col] = vv;
            }
        }
    }
}

extern "C" void kernel_launch(void* const* d_in, const int* in_sizes, int n_in,
                              void* d_out, int out_size, void* d_ws, size_t ws_size,
                              hipStream_t stream) {
    const float* x  = (const float*)d_in[0];
    const int* ei   = (const int*)d_in[1];
    const float* W1 = (const float*)d_in[2];
    const float* b1 = (const float*)d_in[3];
    const float* W2 = (const float*)d_in[4];
    const float* b2 = (const float*)d_in[5];
    const float* W3 = (const float*)d_in[6];
    const float* b3 = (const float*)d_in[7];
    const float* W4 = (const float*)d_in[8];
    const float* b4 = (const float*)d_in[9];
    const float* Wl = (const float*)d_in[10];
    const float* bl = (const float*)d_in[11];
    float* out = (float*)d_out;

    const int* src = ei;
    const int* dst = ei + E_EDGES;

    char* ws = (char*)d_ws;
    const size_t R = (size_t)N_NODES * 256 * 4;        // 51.2e6 B
    float* R1 = (float*)ws;
    float* R2 = (float*)(ws + R);
    float* hF  = R1;                          // [N,128] agg (layer 1 & 2)
    float* h1  = R2;                          // [N,128]
    float* h1b = R2 + (size_t)N_NODES * 128;  // [N,128]
    float* hF2 = R1;
    float* h2  = R2;                          // [N,256]
    float* h2b = R1;                          // [N,256]
    size_t off = 2 * R;
    unsigned short* W1h = (unsigned short*)(ws + off); off += 16384 * 2;
    unsigned short* W1l = (unsigned short*)(ws + off); off += 16384 * 2;
    unsigned short* W2h = (unsigned short*)(ws + off); off += 16384 * 2;
    unsigned short* W2l = (unsigned short*)(ws + off); off += 16384 * 2;
    unsigned short* W3h = (unsigned short*)(ws + off); off += 32768 * 2;
    unsigned short* W3l = (unsigned short*)(ws + off); off += 32768 * 2;
    unsigned short* W4h = (unsigned short*)(ws + off); off += 65536 * 2;
    unsigned short* W4l = (unsigned short*)(ws + off); off += 65536 * 2;
    unsigned short* Wlh = (unsigned short*)(ws + off); off += 12288 * 2;
    unsigned short* Wll = (unsigned short*)(ws + off); off += 12288 * 2;
    off = (off + 255) & ~(size_t)255;
    int* deg    = (int*)(ws + off); off += (size_t)(N_NODES + 1) * 4;
    int* cursor = (int*)(ws + off); off += (size_t)(N_NODES + 1) * 4;
    int* rowptr = (int*)(ws + off); off += (size_t)(N_NODES + 1) * 4;
    unsigned short* perm = (unsigned short*)(ws + off); off += (size_t)E_EDGES * 2;
    off = (off + 255) & ~(size_t)255;
    int* lexcl  = (int*)(ws + off); off += (size_t)N_NODES * 4;
    int* btot   = (int*)(ws + off); off += 64 * 4;
    int* bbase  = (int*)(ws + off); off += 64 * 4;
    (void)ws_size; (void)in_sizes; (void)n_in; (void)out_size;

    const int NB = (N_NODES + 1023) / 1024;

    // ---- CSR build ----
    (void)hipMemsetAsync(deg, 0, (size_t)(N_NODES + 1) * 4, stream);
    hist_deg<<<(E_EDGES + 255) / 256, 256, 0, stream>>>(dst, deg);
    scan1<<<NB, 1024, 0, stream>>>(deg, lexcl, btot);
    scan2<<<1, 64, 0, stream>>>(btot, bbase, NB);
    scan3<<<(N_NODES + 255) / 256, 256, 0, stream>>>(lexcl, bbase, rowptr, cursor);
    fill_csr<<<(E_EDGES + 255) / 256, 256, 0, stream>>>(src, dst, cursor, perm);

    // ---- Weight pre-split ----
    prep_all<<<70, 256, 0, stream>>>(W1, W2, W3, W4, Wl,
                                     W1h, W1l, W2h, W2l, W3h, W3l,
                                     W4h, W4l, Wlh, Wll);

    const int aggBlocks = (N_NODES * 64 + 255) / 256;   // one wave per node
    const int rc2 = (N_NODES + 127) / 128;              // 391 row chunks (RPW=2)
    const int rc1 = (N_NODES + 63) / 64;                // 782 row chunks (RPW=1)

    // ---- Layer 1 ----
    gather_agg<<<aggBlocks, 256, 0, stream>>>(x, rowptr, perm, hF);
    gemm_split<128, 128, 128, true, 2, 2><<<rc2 * 2, 256, 0, stream>>>(hF, W1h, W1l, b1, h1);
    gemm_split<128, 128, 128, true, 2, 2><<<rc2 * 2, 256, 0, stream>>>(h1, W2h, W2l, b2, h1b);

    // ---- Layer 2 ----
    gather_agg<<<aggBlocks, 256, 0, stream>>>(h1b, rowptr, perm, hF2);
    gemm_split<128, 256, 256, true, 2, 2><<<rc2 * 2, 256, 0, stream>>>(hF2, W3h, W3l, b3, h2);
    gemm_split<256, 256, 256, true, 2, 2><<<rc2 * 2, 256, 0, stream>>>(h2, W4h, W4l, b4, h2b);

    // ---- Final linear ----
    gemm_split<256, 48, 40, false, 1, 1><<<rc1, 256, 0, stream>>>(h2b, Wlh, Wll, bl, out);
}